// Round 2
// baseline (1407.125 us; speedup 1.0000x reference)
//
#include <hip/hip_runtime.h>
#include <hip/hip_bf16.h>
#include <stdint.h>

// KVMemoryLayer: scores = x@keys^T (512x200000, K=1024 fp32), top-32/row,
// softmax, weighted gather of vals.
// R2: (1) XCD-group swizzle so 4 row-tile blocks sharing a keys col-tile land
//     on the same XCD L2 (kills the 2x keys over-fetch);
//     (2) __launch_bounds__(256,4) -> 4 blocks/CU for BW;
//     (3) per-(row,coltile) max array -> K2 scans ~60 tiles instead of 200000
//     scores twice.

#define KTOP 32
#define MROWS 512
#define NKEYS 200000
#define DDIM 1024

#define BM 128
#define BN 128
#define BK 64
#define LDT 72          // padded LDS row length in bf16 elems (144 B)
#define NCOLT 1563      // ceil(200000/128)
#define NT 1568         // padded tile count (multiple of 8 for swizzle)
#define TCAP 256
#define CCAP 256
#define TMARGIN 0.125f  // >> 2*bf16-gemm error (~0.004); provable coverage

typedef __attribute__((ext_vector_type(4))) float f32x4;
typedef __attribute__((ext_vector_type(8))) short short8;

__device__ __forceinline__ unsigned short f2bf(float f) {
    unsigned int u = __float_as_uint(f);
    u = (u + 0x7FFFu + ((u >> 16) & 1u)) >> 16;   // RNE, no NaN inputs here
    return (unsigned short)u;
}
__device__ __forceinline__ int enc16(unsigned short u) {       // monotone order-encode
    return (int)(u ^ ((u & 0x8000u) ? 0xFFFFu : 0x8000u));
}
__device__ __forceinline__ float dec_enc(int e) {              // encoded -> float
    unsigned short u = (unsigned short)((e & 0x8000) ? (e ^ 0x8000) : (e ^ 0xFFFF));
    return __uint_as_float((unsigned int)u << 16);
}
__device__ __forceinline__ float bf2f(unsigned short u) {
    return __uint_as_float((unsigned int)u << 16);
}

// ---------------------------------------------------------------- cvt x->bf16
__global__ void cvt_x_kernel(const float* __restrict__ x, unsigned short* __restrict__ xb) {
    int i = blockIdx.x * blockDim.x + threadIdx.x;      // 131072 threads, 4 elems each
    f32x4 v = reinterpret_cast<const f32x4*>(x)[i];
    ushort4 o;
    o.x = f2bf(v.x); o.y = f2bf(v.y); o.z = f2bf(v.z); o.w = f2bf(v.w);
    reinterpret_cast<ushort4*>(xb)[i] = o;
}

// ---------------------------------------------------------------- K1: scores
__global__ __launch_bounds__(256, 4)
void score_gemm(const float* __restrict__ keys, const unsigned short* __restrict__ xb,
                unsigned short* __restrict__ scores, unsigned short* __restrict__ tilemax) {
    __shared__ unsigned short As[BM * LDT];
    __shared__ unsigned short Bs[BN * LDT];
    __shared__ int tmax[BM];

    const int tid  = threadIdx.x;
    const int lane = tid & 63;
    const int wid  = tid >> 6;
    const int wr   = wid >> 1;          // 2x2 wave grid, 64x64 per wave
    const int wc   = wid & 1;

    // XCD-group swizzle: the 4 row-tile blocks of one col-tile get bids that
    // are congruent mod 8 (same XCD under round-robin) and 8 apart (adjacent
    // in time). bid = ((p*4 + rt)*8 + s), g = p*8 + s.
    const int bid = blockIdx.x;
    const int s   = bid & 7;
    const int u   = bid >> 3;
    const int rt  = u & 3;
    const int g   = (u >> 2) * 8 + s;   // col tile 0..1567
    if (g >= NCOLT) return;
    const int row0 = rt * BM;
    const int col0 = g * BN;

    if (tid < BM) tmax[tid] = 0;        // enc 0 < any real finite score's enc

    f32x4 acc[4][4];
#pragma unroll
    for (int m = 0; m < 4; m++)
#pragma unroll
        for (int n = 0; n < 4; n++) acc[m][n] = (f32x4){0.f, 0.f, 0.f, 0.f};

    short8 areg[4];
    f32x4  breg[8];

    auto loadA = [&](int k0) {
#pragma unroll
        for (int i = 0; i < 4; i++) {
            int c = i * 256 + tid;                 // 0..1023  (16B chunks of A tile)
            int r = c >> 3, j = c & 7;
            areg[i] = *reinterpret_cast<const short8*>(xb + (size_t)(row0 + r) * DDIM + k0 + j * 8);
        }
    };
    auto loadB = [&](int k0) {
#pragma unroll
        for (int i = 0; i < 8; i++) {
            int c = i * 256 + tid;                 // 0..2047  (float4 chunks of B tile)
            int r = c >> 4, j = c & 15;
            int gr = col0 + r; gr = (gr < NKEYS) ? gr : (NKEYS - 1);   // clamp OOB cols
            breg[i] = *reinterpret_cast<const f32x4*>(keys + (size_t)gr * DDIM + k0 + j * 4);
        }
    };
    auto writeLDS = [&]() {
#pragma unroll
        for (int i = 0; i < 4; i++) {
            int c = i * 256 + tid;
            int r = c >> 3, j = c & 7;
            *reinterpret_cast<short8*>(&As[r * LDT + j * 8]) = areg[i];
        }
#pragma unroll
        for (int i = 0; i < 8; i++) {
            int c = i * 256 + tid;
            int r = c >> 4, j = c & 15;
            ushort4 o;
            o.x = f2bf(breg[i].x); o.y = f2bf(breg[i].y);
            o.z = f2bf(breg[i].z); o.w = f2bf(breg[i].w);
            *reinterpret_cast<ushort4*>(&Bs[r * LDT + j * 4]) = o;
        }
    };

    const int rl = lane & 15;
    const int kl = (lane >> 4) * 8;

    auto compute = [&]() {
        const unsigned short* Ab = &As[(wr * 64 + rl) * LDT + kl];
        const unsigned short* Bb = &Bs[(wc * 64 + rl) * LDT + kl];
#pragma unroll
        for (int kk = 0; kk < BK; kk += 32) {
            short8 af[4], bf[4];
#pragma unroll
            for (int m = 0; m < 4; m++) af[m] = *reinterpret_cast<const short8*>(Ab + m * 16 * LDT + kk);
#pragma unroll
            for (int n = 0; n < 4; n++) bf[n] = *reinterpret_cast<const short8*>(Bb + n * 16 * LDT + kk);
#pragma unroll
            for (int m = 0; m < 4; m++)
#pragma unroll
                for (int n = 0; n < 4; n++)
                    acc[m][n] = __builtin_amdgcn_mfma_f32_16x16x32_bf16(af[m], bf[n], acc[m][n], 0, 0, 0);
        }
    };

    loadA(0); loadB(0);
    for (int t = 0; t < DDIM / BK; t++) {
        __syncthreads();                 // previous compute done; LDS reusable
        writeLDS();
        __syncthreads();
        if (t + 1 < DDIM / BK) { loadA((t + 1) * BK); loadB((t + 1) * BK); }  // overlap w/ MFMA
        compute();
    }

    // epilogue: store bf16 scores (predicated) + per-(row,tile) max
    const int rg = lane >> 4;
#pragma unroll
    for (int m = 0; m < 4; m++) {
#pragma unroll
        for (int j = 0; j < 4; j++) {
            int lrow = wr * 64 + m * 16 + rg * 4 + j;
            int grow = row0 + lrow;
            float mx = -1e30f;
#pragma unroll
            for (int n = 0; n < 4; n++) {
                float v = acc[m][n][j];
                mx = fmaxf(mx, v);      // OOB lanes duplicate key NKEYS-1 (valid, in-tile)
                int gcol = col0 + wc * 64 + n * 16 + rl;
                if (gcol < NKEYS)
                    scores[(size_t)grow * NKEYS + gcol] = f2bf(v);
            }
#pragma unroll
            for (int sft = 1; sft < 16; sft <<= 1) mx = fmaxf(mx, __shfl_xor(mx, sft));
            if (rl == 0)
                atomicMax(&tmax[lrow], enc16(f2bf(mx)));
        }
    }
    __syncthreads();
    if (tid < BM)
        tilemax[(size_t)(row0 + tid) * NT + g] = (unsigned short)tmax[tid];
}

// ------------------------------------------------- K2: select+refine+output
__global__ __launch_bounds__(256)
void select_kernel(const float* __restrict__ x, const float* __restrict__ keys,
                   const float* __restrict__ vals, const unsigned short* __restrict__ scores,
                   const unsigned short* __restrict__ tilemax, float* __restrict__ out) {
    const int n    = blockIdx.x;
    const int tid  = threadIdx.x;
    const int lane = tid & 63;
    const int w    = tid >> 6;

    __shared__ __align__(16) float qs[DDIM];
    __shared__ unsigned short enc_t[NT];
    __shared__ int    hist[256];
    __shared__ int    tiles[TCAP];
    __shared__ int    cand[CCAP];
    __shared__ double rsc[CCAP];
    __shared__ float  wgt[KTOP];
    __shared__ int    topslot[KTOP];
    __shared__ float  topval[KTOP];
    __shared__ int    ntiles, ncand, sbsel, sabove, st32e;

    reinterpret_cast<f32x4*>(qs)[tid] = reinterpret_cast<const f32x4*>(x + (size_t)n * DDIM)[tid];
    hist[tid] = 0;
    if (tid < 32) { wgt[tid] = 0.f; topslot[tid] = -1; }
    if (tid == 0) { ntiles = 0; ncand = 0; }
    // load tile-max row (encoded bf16); phantom tiles are enc=0 (below everything)
    {
        const uint4* tm = reinterpret_cast<const uint4*>(tilemax + (size_t)n * NT);
        uint4* dst = reinterpret_cast<uint4*>(enc_t);
        for (int c = tid; c < NT / 8; c += 256) dst[c] = tm[c];
    }
    __syncthreads();

    // --- exact 32nd-largest tile-max via two-level 8-bit radix ---
    for (int i = tid; i < NT; i += 256) atomicAdd(&hist[enc_t[i] >> 8], 1);
    __syncthreads();
    if (tid == 0) {
        int cum = 0, b = 255;
        for (; b >= 0; b--) { cum += hist[b]; if (cum >= KTOP) break; }
        sbsel = b; sabove = cum - hist[b];
    }
    __syncthreads();
    const int bsel = sbsel;
    hist[tid] = 0;
    __syncthreads();
    for (int i = tid; i < NT; i += 256) {
        int e = enc_t[i];
        if ((e >> 8) == bsel) atomicAdd(&hist[e & 0xFF], 1);
    }
    __syncthreads();
    if (tid == 0) {
        int cum = sabove, lb = 255;
        for (; lb >= 0; lb--) { cum += hist[lb]; if (cum >= KTOP) break; }
        st32e = (bsel << 8) | lb;
    }
    __syncthreads();
    const float thr = dec_enc(st32e) - TMARGIN;   // covers exact top-32 (margin >> 2*delta)

    // --- select tiles with max >= thr ---
    for (int i = tid; i < NT; i += 256) {
        if (dec_enc(enc_t[i]) >= thr) {
            int p = atomicAdd(&ntiles, 1);
            if (p < TCAP) tiles[p] = i;
        }
    }
    __syncthreads();
    const int nt = ntiles < TCAP ? ntiles : TCAP;

    // --- scan selected tiles, collect candidates >= thr ---
    for (int idx = tid; idx < nt * BN; idx += 256) {
        int col = tiles[idx >> 7] * BN + (idx & 127);
        if (col < NKEYS) {
            float v = bf2f(scores[(size_t)n * NKEYS + col]);
            if (v >= thr) {
                int p = atomicAdd(&ncand, 1);
                if (p < CCAP) cand[p] = col;
            }
        }
    }
    __syncthreads();
    const int cnt = ncand < CCAP ? ncand : CCAP;

    // --- refine: exact dot(x_row, keys[cand]) with f64 accum, one wave/cand ---
    for (int ci = w; ci < cnt; ci += 4) {
        const f32x4* kv = reinterpret_cast<const f32x4*>(keys + (size_t)cand[ci] * DDIM) + lane * 4;
        const f32x4* qv = reinterpret_cast<const f32x4*>(qs) + lane * 4;
        double a = 0.0;
#pragma unroll
        for (int i = 0; i < 4; i++) {
            f32x4 q = qv[i], k = kv[i];
            a += (double)q.x * k.x + (double)q.y * k.y + (double)q.z * k.z + (double)q.w * k.w;
        }
#pragma unroll
        for (int sft = 32; sft >= 1; sft >>= 1) a += __shfl_xor(a, sft);
        if (lane == 0) rsc[ci] = a;
    }
    __syncthreads();

    // --- exact top-32 among candidates (wave 0, 4 slots covers CCAP=256) ---
    if (w == 0) {
        double v0[4]; int id0[4];
#pragma unroll
        for (int sft = 0; sft < 4; sft++) {
            int p = lane + sft * 64;
            if (p < cnt) { v0[sft] = rsc[p]; id0[sft] = p; } else { v0[sft] = -1e300; id0[sft] = -1; }
        }
        for (int k = 0; k < KTOP; k++) {
            double bv = v0[0]; int bi = id0[0];
#pragma unroll
            for (int sft = 1; sft < 4; sft++) if (v0[sft] > bv) { bv = v0[sft]; bi = id0[sft]; }
#pragma unroll
            for (int sft = 32; sft >= 1; sft >>= 1) {
                double ov = __shfl_xor(bv, sft);
                int    oi = __shfl_xor(bi, sft);
                if (ov > bv) { bv = ov; bi = oi; }
            }
            if (lane == 0) { topslot[k] = bi; topval[k] = (float)bv; }
#pragma unroll
            for (int sft = 0; sft < 4; sft++) if (bi >= 0 && id0[sft] == bi) v0[sft] = -1e300;
        }
    }
    __syncthreads();

    // --- softmax over the 32 exact scores ---
    if (tid == 0) {
        float mx = topval[0];
        float sum = 0.f;
        for (int k = 0; k < KTOP; k++) {
            float e = (topslot[k] >= 0) ? expf(topval[k] - mx) : 0.f;
            wgt[k] = e; sum += e;
        }
        float inv = 1.f / sum;
        for (int k = 0; k < KTOP; k++) wgt[k] *= inv;
    }
    __syncthreads();

    // --- output: weighted sum of selected vals rows ---
    f32x4 accv = (f32x4){0.f, 0.f, 0.f, 0.f};
    for (int k = 0; k < KTOP; k++) {
        int sl = topslot[k];
        if (sl >= 0) {
            float wk = wgt[k];
            f32x4 v = reinterpret_cast<const f32x4*>(vals + (size_t)cand[sl] * DDIM)[tid];
            accv.x += wk * v.x; accv.y += wk * v.y; accv.z += wk * v.z; accv.w += wk * v.w;
        }
    }
    reinterpret_cast<f32x4*>(out + (size_t)n * DDIM)[tid] = accv;
}

// ---------------------------------------------------------------- launch
extern "C" void kernel_launch(void* const* d_in, const int* in_sizes, int n_in,
                              void* d_out, int out_size, void* d_ws, size_t ws_size,
                              hipStream_t stream) {
    const float* x    = (const float*)d_in[0];
    const float* keys = (const float*)d_in[1];
    const float* vals = (const float*)d_in[2];
    float* out = (float*)d_out;

    char* ws = (char*)d_ws;
    unsigned short* scores  = (unsigned short*)ws;                         // 204,800,000 B
    unsigned short* xb      = (unsigned short*)(ws + 204800000);           //   1,048,576 B
    unsigned short* tilemax = (unsigned short*)(ws + 204800000 + 1048576); //   1,605,632 B

    hipMemsetAsync(tilemax, 0, (size_t)MROWS * NT * sizeof(unsigned short), stream);
    cvt_x_kernel<<<512, 256, 0, stream>>>(x, xb);
    score_gemm<<<4 * NT, 256, 0, stream>>>(keys, xb, scores, tilemax);
    select_kernel<<<MROWS, 256, 0, stream>>>(x, keys, vals, scores, tilemax, out);
}

// Round 3
// 476.441 us; speedup vs baseline: 2.9534x; 2.9534x over previous
//
#include <hip/hip_runtime.h>
#include <hip/hip_bf16.h>
#include <stdint.h>

// KVMemoryLayer: scores = x@keys^T (512x200000, K=1024 fp32), top-32/row,
// softmax, weighted gather of vals.
// R3: revert launch_bounds to (256,2) (R2's (256,4) caused a VGPR-spill cliff:
//     +1.8GB scratch writes); keep XCD-group swizzle + tilemax select;
//     fp32->bf16 staging via hardware v_cvt (__float2bfloat16) instead of
//     3-op integer hand-roll.

#define KTOP 32
#define MROWS 512
#define NKEYS 200000
#define DDIM 1024

#define BM 128
#define BN 128
#define BK 64
#define LDT 72          // padded LDS row length in bf16 elems (144 B)
#define NCOLT 1563      // ceil(200000/128)
#define NT 1568         // padded tile count (multiple of 8 for swizzle)
#define TCAP 256
#define CCAP 256
#define TMARGIN 0.125f  // >> 2*bf16-gemm error (~0.004); provable coverage

typedef __attribute__((ext_vector_type(4))) float f32x4;
typedef __attribute__((ext_vector_type(8))) short short8;

__device__ __forceinline__ unsigned short f2bf(float f) {      // hw RNE cvt
    __hip_bfloat16 h = __float2bfloat16(f);
    return *reinterpret_cast<unsigned short*>(&h);
}
__device__ __forceinline__ int enc16(unsigned short u) {       // monotone order-encode
    return (int)(u ^ ((u & 0x8000u) ? 0xFFFFu : 0x8000u));
}
__device__ __forceinline__ float dec_enc(int e) {              // encoded -> float
    unsigned short u = (unsigned short)((e & 0x8000) ? (e ^ 0x8000) : (e ^ 0xFFFF));
    return __uint_as_float((unsigned int)u << 16);
}
__device__ __forceinline__ float bf2f(unsigned short u) {
    return __uint_as_float((unsigned int)u << 16);
}

// ---------------------------------------------------------------- cvt x->bf16
__global__ void cvt_x_kernel(const float* __restrict__ x, unsigned short* __restrict__ xb) {
    int i = blockIdx.x * blockDim.x + threadIdx.x;      // 131072 threads, 4 elems each
    f32x4 v = reinterpret_cast<const f32x4*>(x)[i];
    ushort4 o;
    o.x = f2bf(v.x); o.y = f2bf(v.y); o.z = f2bf(v.z); o.w = f2bf(v.w);
    reinterpret_cast<ushort4*>(xb)[i] = o;
}

// ---------------------------------------------------------------- K1: scores
__global__ __launch_bounds__(256, 2)
void score_gemm(const float* __restrict__ keys, const unsigned short* __restrict__ xb,
                unsigned short* __restrict__ scores, unsigned short* __restrict__ tilemax) {
    __shared__ unsigned short As[BM * LDT];
    __shared__ unsigned short Bs[BN * LDT];
    __shared__ int tmax[BM];

    const int tid  = threadIdx.x;
    const int lane = tid & 63;
    const int wid  = tid >> 6;
    const int wr   = wid >> 1;          // 2x2 wave grid, 64x64 per wave
    const int wc   = wid & 1;

    // XCD-group swizzle: the 4 row-tile blocks of one col-tile get bids that
    // are congruent mod 8 (same XCD under round-robin) and 8 apart (adjacent
    // in time). bid = ((p*4 + rt)*8 + s), g = p*8 + s.
    const int bid = blockIdx.x;
    const int s   = bid & 7;
    const int u   = bid >> 3;
    const int rt  = u & 3;
    const int g   = (u >> 2) * 8 + s;   // col tile 0..1567
    if (g >= NCOLT) return;
    const int row0 = rt * BM;
    const int col0 = g * BN;

    if (tid < BM) tmax[tid] = 0;        // enc 0 < any real finite score's enc

    f32x4 acc[4][4];
#pragma unroll
    for (int m = 0; m < 4; m++)
#pragma unroll
        for (int n = 0; n < 4; n++) acc[m][n] = (f32x4){0.f, 0.f, 0.f, 0.f};

    short8 areg[4];
    f32x4  breg[8];

    auto loadA = [&](int k0) {
#pragma unroll
        for (int i = 0; i < 4; i++) {
            int c = i * 256 + tid;                 // 0..1023  (16B chunks of A tile)
            int r = c >> 3, j = c & 7;
            areg[i] = *reinterpret_cast<const short8*>(xb + (size_t)(row0 + r) * DDIM + k0 + j * 8);
        }
    };
    auto loadB = [&](int k0) {
#pragma unroll
        for (int i = 0; i < 8; i++) {
            int c = i * 256 + tid;                 // 0..2047  (float4 chunks of B tile)
            int r = c >> 4, j = c & 15;
            int gr = col0 + r; gr = (gr < NKEYS) ? gr : (NKEYS - 1);   // clamp OOB cols
            breg[i] = *reinterpret_cast<const f32x4*>(keys + (size_t)gr * DDIM + k0 + j * 4);
        }
    };
    auto writeLDS = [&]() {
#pragma unroll
        for (int i = 0; i < 4; i++) {
            int c = i * 256 + tid;
            int r = c >> 3, j = c & 7;
            *reinterpret_cast<short8*>(&As[r * LDT + j * 8]) = areg[i];
        }
#pragma unroll
        for (int i = 0; i < 8; i++) {
            int c = i * 256 + tid;
            int r = c >> 4, j = c & 15;
            ushort4 o;
            o.x = f2bf(breg[i].x); o.y = f2bf(breg[i].y);
            o.z = f2bf(breg[i].z); o.w = f2bf(breg[i].w);
            *reinterpret_cast<ushort4*>(&Bs[r * LDT + j * 4]) = o;
        }
    };

    const int rl = lane & 15;
    const int kl = (lane >> 4) * 8;

    auto compute = [&]() {
        const unsigned short* Ab = &As[(wr * 64 + rl) * LDT + kl];
        const unsigned short* Bb = &Bs[(wc * 64 + rl) * LDT + kl];
#pragma unroll
        for (int kk = 0; kk < BK; kk += 32) {
            short8 af[4], bf[4];
#pragma unroll
            for (int m = 0; m < 4; m++) af[m] = *reinterpret_cast<const short8*>(Ab + m * 16 * LDT + kk);
#pragma unroll
            for (int n = 0; n < 4; n++) bf[n] = *reinterpret_cast<const short8*>(Bb + n * 16 * LDT + kk);
#pragma unroll
            for (int m = 0; m < 4; m++)
#pragma unroll
                for (int n = 0; n < 4; n++)
                    acc[m][n] = __builtin_amdgcn_mfma_f32_16x16x32_bf16(af[m], bf[n], acc[m][n], 0, 0, 0);
        }
    };

    loadA(0); loadB(0);
    for (int t = 0; t < DDIM / BK; t++) {
        __syncthreads();                 // previous compute done; LDS reusable
        writeLDS();
        __syncthreads();
        if (t + 1 < DDIM / BK) { loadA((t + 1) * BK); loadB((t + 1) * BK); }  // overlap w/ MFMA
        compute();
    }

    // epilogue: store bf16 scores (predicated) + per-(row,tile) max
    const int rg = lane >> 4;
#pragma unroll
    for (int m = 0; m < 4; m++) {
#pragma unroll
        for (int j = 0; j < 4; j++) {
            int lrow = wr * 64 + m * 16 + rg * 4 + j;
            int grow = row0 + lrow;
            float mx = -1e30f;
#pragma unroll
            for (int n = 0; n < 4; n++) {
                float v = acc[m][n][j];
                mx = fmaxf(mx, v);      // OOB lanes duplicate key NKEYS-1 (valid, in-tile)
                int gcol = col0 + wc * 64 + n * 16 + rl;
                if (gcol < NKEYS)
                    scores[(size_t)grow * NKEYS + gcol] = f2bf(v);
            }
#pragma unroll
            for (int sft = 1; sft < 16; sft <<= 1) mx = fmaxf(mx, __shfl_xor(mx, sft));
            if (rl == 0)
                atomicMax(&tmax[lrow], enc16(f2bf(mx)));
        }
    }
    __syncthreads();
    if (tid < BM)
        tilemax[(size_t)(row0 + tid) * NT + g] = (unsigned short)tmax[tid];
}

// ------------------------------------------------- K2: select+refine+output
__global__ __launch_bounds__(256)
void select_kernel(const float* __restrict__ x, const float* __restrict__ keys,
                   const float* __restrict__ vals, const unsigned short* __restrict__ scores,
                   const unsigned short* __restrict__ tilemax, float* __restrict__ out) {
    const int n    = blockIdx.x;
    const int tid  = threadIdx.x;
    const int lane = tid & 63;
    const int w    = tid >> 6;

    __shared__ __align__(16) float qs[DDIM];
    __shared__ unsigned short enc_t[NT];
    __shared__ int    hist[256];
    __shared__ int    tiles[TCAP];
    __shared__ int    cand[CCAP];
    __shared__ double rsc[CCAP];
    __shared__ float  wgt[KTOP];
    __shared__ int    topslot[KTOP];
    __shared__ float  topval[KTOP];
    __shared__ int    ntiles, ncand, sbsel, sabove, st32e;

    reinterpret_cast<f32x4*>(qs)[tid] = reinterpret_cast<const f32x4*>(x + (size_t)n * DDIM)[tid];
    hist[tid] = 0;
    if (tid < 32) { wgt[tid] = 0.f; topslot[tid] = -1; }
    if (tid == 0) { ntiles = 0; ncand = 0; }
    // load tile-max row (encoded bf16); phantom tiles are enc=0 (below everything)
    {
        const uint4* tm = reinterpret_cast<const uint4*>(tilemax + (size_t)n * NT);
        uint4* dst = reinterpret_cast<uint4*>(enc_t);
        for (int c = tid; c < NT / 8; c += 256) dst[c] = tm[c];
    }
    __syncthreads();

    // --- exact 32nd-largest tile-max via two-level 8-bit radix ---
    for (int i = tid; i < NT; i += 256) atomicAdd(&hist[enc_t[i] >> 8], 1);
    __syncthreads();
    if (tid == 0) {
        int cum = 0, b = 255;
        for (; b >= 0; b--) { cum += hist[b]; if (cum >= KTOP) break; }
        sbsel = b; sabove = cum - hist[b];
    }
    __syncthreads();
    const int bsel = sbsel;
    hist[tid] = 0;
    __syncthreads();
    for (int i = tid; i < NT; i += 256) {
        int e = enc_t[i];
        if ((e >> 8) == bsel) atomicAdd(&hist[e & 0xFF], 1);
    }
    __syncthreads();
    if (tid == 0) {
        int cum = sabove, lb = 255;
        for (; lb >= 0; lb--) { cum += hist[lb]; if (cum >= KTOP) break; }
        st32e = (bsel << 8) | lb;
    }
    __syncthreads();
    const float thr = dec_enc(st32e) - TMARGIN;   // covers exact top-32 (margin >> 2*delta)

    // --- select tiles with max >= thr ---
    for (int i = tid; i < NT; i += 256) {
        if (dec_enc(enc_t[i]) >= thr) {
            int p = atomicAdd(&ntiles, 1);
            if (p < TCAP) tiles[p] = i;
        }
    }
    __syncthreads();
    const int nt = ntiles < TCAP ? ntiles : TCAP;

    // --- scan selected tiles, collect candidates >= thr ---
    for (int idx = tid; idx < nt * BN; idx += 256) {
        int col = tiles[idx >> 7] * BN + (idx & 127);
        if (col < NKEYS) {
            float v = bf2f(scores[(size_t)n * NKEYS + col]);
            if (v >= thr) {
                int p = atomicAdd(&ncand, 1);
                if (p < CCAP) cand[p] = col;
            }
        }
    }
    __syncthreads();
    const int cnt = ncand < CCAP ? ncand : CCAP;

    // --- refine: exact dot(x_row, keys[cand]) with f64 accum, one wave/cand ---
    for (int ci = w; ci < cnt; ci += 4) {
        const f32x4* kv = reinterpret_cast<const f32x4*>(keys + (size_t)cand[ci] * DDIM) + lane * 4;
        const f32x4* qv = reinterpret_cast<const f32x4*>(qs) + lane * 4;
        double a = 0.0;
#pragma unroll
        for (int i = 0; i < 4; i++) {
            f32x4 q = qv[i], k = kv[i];
            a += (double)q.x * k.x + (double)q.y * k.y + (double)q.z * k.z + (double)q.w * k.w;
        }
#pragma unroll
        for (int sft = 32; sft >= 1; sft >>= 1) a += __shfl_xor(a, sft);
        if (lane == 0) rsc[ci] = a;
    }
    __syncthreads();

    // --- exact top-32 among candidates (wave 0, 4 slots covers CCAP=256) ---
    if (w == 0) {
        double v0[4]; int id0[4];
#pragma unroll
        for (int sft = 0; sft < 4; sft++) {
            int p = lane + sft * 64;
            if (p < cnt) { v0[sft] = rsc[p]; id0[sft] = p; } else { v0[sft] = -1e300; id0[sft] = -1; }
        }
        for (int k = 0; k < KTOP; k++) {
            double bv = v0[0]; int bi = id0[0];
#pragma unroll
            for (int sft = 1; sft < 4; sft++) if (v0[sft] > bv) { bv = v0[sft]; bi = id0[sft]; }
#pragma unroll
            for (int sft = 32; sft >= 1; sft >>= 1) {
                double ov = __shfl_xor(bv, sft);
                int    oi = __shfl_xor(bi, sft);
                if (ov > bv) { bv = ov; bi = oi; }
            }
            if (lane == 0) { topslot[k] = bi; topval[k] = (float)bv; }
#pragma unroll
            for (int sft = 0; sft < 4; sft++) if (bi >= 0 && id0[sft] == bi) v0[sft] = -1e300;
        }
    }
    __syncthreads();

    // --- softmax over the 32 exact scores ---
    if (tid == 0) {
        float mx = topval[0];
        float sum = 0.f;
        for (int k = 0; k < KTOP; k++) {
            float e = (topslot[k] >= 0) ? expf(topval[k] - mx) : 0.f;
            wgt[k] = e; sum += e;
        }
        float inv = 1.f / sum;
        for (int k = 0; k < KTOP; k++) wgt[k] *= inv;
    }
    __syncthreads();

    // --- output: weighted sum of selected vals rows ---
    f32x4 accv = (f32x4){0.f, 0.f, 0.f, 0.f};
    for (int k = 0; k < KTOP; k++) {
        int sl = topslot[k];
        if (sl >= 0) {
            float wk = wgt[k];
            f32x4 v = reinterpret_cast<const f32x4*>(vals + (size_t)cand[sl] * DDIM)[tid];
            accv.x += wk * v.x; accv.y += wk * v.y; accv.z += wk * v.z; accv.w += wk * v.w;
        }
    }
    reinterpret_cast<f32x4*>(out + (size_t)n * DDIM)[tid] = accv;
}

// ---------------------------------------------------------------- launch
extern "C" void kernel_launch(void* const* d_in, const int* in_sizes, int n_in,
                              void* d_out, int out_size, void* d_ws, size_t ws_size,
                              hipStream_t stream) {
    const float* x    = (const float*)d_in[0];
    const float* keys = (const float*)d_in[1];
    const float* vals = (const float*)d_in[2];
    float* out = (float*)d_out;

    char* ws = (char*)d_ws;
    unsigned short* scores  = (unsigned short*)ws;                         // 204,800,000 B
    unsigned short* xb      = (unsigned short*)(ws + 204800000);           //   1,048,576 B
    unsigned short* tilemax = (unsigned short*)(ws + 204800000 + 1048576); //   1,605,632 B

    hipMemsetAsync(tilemax, 0, (size_t)MROWS * NT * sizeof(unsigned short), stream);
    cvt_x_kernel<<<512, 256, 0, stream>>>(x, xb);
    score_gemm<<<4 * NT, 256, 0, stream>>>(keys, xb, scores, tilemax);
    select_kernel<<<MROWS, 256, 0, stream>>>(x, keys, vals, scores, tilemax, out);
}

// Round 4
// 475.532 us; speedup vs baseline: 2.9591x; 1.0019x over previous
//
#include <hip/hip_runtime.h>
#include <hip/hip_bf16.h>
#include <stdint.h>

// KVMemoryLayer: scores = x@keys^T (512x200000, K=1024 fp32), top-32/row,
// softmax, weighted gather of vals.
// R4: (1) __launch_bounds__(256,3): VGPR104+AGPR64=168 <= 170-reg budget for
//     3 waves/SIMD -> 3 blocks/CU (was pinned at 2); latency hiding for the
//     B-prefetch. (2) drop tilemax memset; K2 treats phantom tiles as -inf.

#define KTOP 32
#define MROWS 512
#define NKEYS 200000
#define DDIM 1024

#define BM 128
#define BN 128
#define BK 64
#define LDT 72          // padded LDS row length in bf16 elems (144 B)
#define NCOLT 1563      // ceil(200000/128)
#define NT 1568         // padded tile count (multiple of 8 for swizzle)
#define TCAP 256
#define CCAP 256
#define TMARGIN 0.125f  // >> 2*bf16-gemm error (~0.004); provable coverage

typedef __attribute__((ext_vector_type(4))) float f32x4;
typedef __attribute__((ext_vector_type(8))) short short8;

__device__ __forceinline__ unsigned short f2bf(float f) {      // hw RNE cvt
    __hip_bfloat16 h = __float2bfloat16(f);
    return *reinterpret_cast<unsigned short*>(&h);
}
__device__ __forceinline__ int enc16(unsigned short u) {       // monotone order-encode
    return (int)(u ^ ((u & 0x8000u) ? 0xFFFFu : 0x8000u));
}
__device__ __forceinline__ float dec_enc(int e) {              // encoded -> float
    unsigned short u = (unsigned short)((e & 0x8000) ? (e ^ 0x8000) : (e ^ 0xFFFF));
    return __uint_as_float((unsigned int)u << 16);
}
__device__ __forceinline__ float bf2f(unsigned short u) {
    return __uint_as_float((unsigned int)u << 16);
}

// ---------------------------------------------------------------- cvt x->bf16
__global__ void cvt_x_kernel(const float* __restrict__ x, unsigned short* __restrict__ xb) {
    int i = blockIdx.x * blockDim.x + threadIdx.x;      // 131072 threads, 4 elems each
    f32x4 v = reinterpret_cast<const f32x4*>(x)[i];
    ushort4 o;
    o.x = f2bf(v.x); o.y = f2bf(v.y); o.z = f2bf(v.z); o.w = f2bf(v.w);
    reinterpret_cast<ushort4*>(xb)[i] = o;
}

// ---------------------------------------------------------------- K1: scores
__global__ __launch_bounds__(256, 3)
void score_gemm(const float* __restrict__ keys, const unsigned short* __restrict__ xb,
                unsigned short* __restrict__ scores, unsigned short* __restrict__ tilemax) {
    __shared__ unsigned short As[BM * LDT];
    __shared__ unsigned short Bs[BN * LDT];
    __shared__ int tmax[BM];

    const int tid  = threadIdx.x;
    const int lane = tid & 63;
    const int wid  = tid >> 6;
    const int wr   = wid >> 1;          // 2x2 wave grid, 64x64 per wave
    const int wc   = wid & 1;

    // XCD-group swizzle: the 4 row-tile blocks of one col-tile get bids that
    // are congruent mod 8 (same XCD under round-robin) and 8 apart (adjacent
    // in time). bid = ((p*4 + rt)*8 + s), g = p*8 + s.
    const int bid = blockIdx.x;
    const int s   = bid & 7;
    const int u   = bid >> 3;
    const int rt  = u & 3;
    const int g   = (u >> 2) * 8 + s;   // col tile 0..1567
    if (g >= NCOLT) return;
    const int row0 = rt * BM;
    const int col0 = g * BN;

    if (tid < BM) tmax[tid] = 0;        // enc 0 < any real finite score's enc

    f32x4 acc[4][4];
#pragma unroll
    for (int m = 0; m < 4; m++)
#pragma unroll
        for (int n = 0; n < 4; n++) acc[m][n] = (f32x4){0.f, 0.f, 0.f, 0.f};

    short8 areg[4];
    f32x4  breg[8];

    auto loadA = [&](int k0) {
#pragma unroll
        for (int i = 0; i < 4; i++) {
            int c = i * 256 + tid;                 // 0..1023  (16B chunks of A tile)
            int r = c >> 3, j = c & 7;
            areg[i] = *reinterpret_cast<const short8*>(xb + (size_t)(row0 + r) * DDIM + k0 + j * 8);
        }
    };
    auto loadB = [&](int k0) {
#pragma unroll
        for (int i = 0; i < 8; i++) {
            int c = i * 256 + tid;                 // 0..2047  (float4 chunks of B tile)
            int r = c >> 4, j = c & 15;
            int gr = col0 + r; gr = (gr < NKEYS) ? gr : (NKEYS - 1);   // clamp OOB cols
            breg[i] = *reinterpret_cast<const f32x4*>(keys + (size_t)gr * DDIM + k0 + j * 4);
        }
    };
    auto writeLDS = [&]() {
#pragma unroll
        for (int i = 0; i < 4; i++) {
            int c = i * 256 + tid;
            int r = c >> 3, j = c & 7;
            *reinterpret_cast<short8*>(&As[r * LDT + j * 8]) = areg[i];
        }
#pragma unroll
        for (int i = 0; i < 8; i++) {
            int c = i * 256 + tid;
            int r = c >> 4, j = c & 15;
            ushort4 o;
            o.x = f2bf(breg[i].x); o.y = f2bf(breg[i].y);
            o.z = f2bf(breg[i].z); o.w = f2bf(breg[i].w);
            *reinterpret_cast<ushort4*>(&Bs[r * LDT + j * 4]) = o;
        }
    };

    const int rl = lane & 15;
    const int kl = (lane >> 4) * 8;

    auto compute = [&]() {
        const unsigned short* Ab = &As[(wr * 64 + rl) * LDT + kl];
        const unsigned short* Bb = &Bs[(wc * 64 + rl) * LDT + kl];
#pragma unroll
        for (int kk = 0; kk < BK; kk += 32) {
            short8 af[4], bf[4];
#pragma unroll
            for (int m = 0; m < 4; m++) af[m] = *reinterpret_cast<const short8*>(Ab + m * 16 * LDT + kk);
#pragma unroll
            for (int n = 0; n < 4; n++) bf[n] = *reinterpret_cast<const short8*>(Bb + n * 16 * LDT + kk);
#pragma unroll
            for (int m = 0; m < 4; m++)
#pragma unroll
                for (int n = 0; n < 4; n++)
                    acc[m][n] = __builtin_amdgcn_mfma_f32_16x16x32_bf16(af[m], bf[n], acc[m][n], 0, 0, 0);
        }
    };

    loadA(0); loadB(0);
    for (int t = 0; t < DDIM / BK; t++) {
        __syncthreads();                 // previous compute done; LDS reusable
        writeLDS();
        __syncthreads();
        if (t + 1 < DDIM / BK) { loadA((t + 1) * BK); loadB((t + 1) * BK); }  // overlap w/ MFMA
        compute();
    }

    // epilogue: store bf16 scores (predicated) + per-(row,tile) max
    const int rg = lane >> 4;
#pragma unroll
    for (int m = 0; m < 4; m++) {
#pragma unroll
        for (int j = 0; j < 4; j++) {
            int lrow = wr * 64 + m * 16 + rg * 4 + j;
            int grow = row0 + lrow;
            float mx = -1e30f;
#pragma unroll
            for (int n = 0; n < 4; n++) {
                float v = acc[m][n][j];
                mx = fmaxf(mx, v);      // OOB lanes duplicate key NKEYS-1 (valid, in-tile)
                int gcol = col0 + wc * 64 + n * 16 + rl;
                if (gcol < NKEYS)
                    scores[(size_t)grow * NKEYS + gcol] = f2bf(v);
            }
#pragma unroll
            for (int sft = 1; sft < 16; sft <<= 1) mx = fmaxf(mx, __shfl_xor(mx, sft));
            if (rl == 0)
                atomicMax(&tmax[lrow], enc16(f2bf(mx)));
        }
    }
    __syncthreads();
    if (tid < BM)
        tilemax[(size_t)(row0 + tid) * NT + g] = (unsigned short)tmax[tid];
}

// ------------------------------------------------- K2: select+refine+output
__global__ __launch_bounds__(256)
void select_kernel(const float* __restrict__ x, const float* __restrict__ keys,
                   const float* __restrict__ vals, const unsigned short* __restrict__ scores,
                   const unsigned short* __restrict__ tilemax, float* __restrict__ out) {
    const int n    = blockIdx.x;
    const int tid  = threadIdx.x;
    const int lane = tid & 63;
    const int w    = tid >> 6;

    __shared__ __align__(16) float qs[DDIM];
    __shared__ unsigned short enc_t[NT];
    __shared__ int    hist[256];
    __shared__ int    tiles[TCAP];
    __shared__ int    cand[CCAP];
    __shared__ double rsc[CCAP];
    __shared__ float  wgt[KTOP];
    __shared__ int    topslot[KTOP];
    __shared__ float  topval[KTOP];
    __shared__ int    ntiles, ncand, sbsel, sabove, st32e;

    reinterpret_cast<f32x4*>(qs)[tid] = reinterpret_cast<const f32x4*>(x + (size_t)n * DDIM)[tid];
    hist[tid] = 0;
    if (tid < 32) { wgt[tid] = 0.f; topslot[tid] = -1; }
    if (tid == 0) { ntiles = 0; ncand = 0; }
    // load tile-max row (encoded bf16); phantom tiles (>=NCOLT) forced to 0
    // (never written by score_gemm; ws region holds harness poison)
    for (int i = tid; i < NT; i += 256)
        enc_t[i] = (i < NCOLT) ? tilemax[(size_t)n * NT + i] : 0;
    __syncthreads();

    // --- exact 32nd-largest tile-max via two-level 8-bit radix ---
    for (int i = tid; i < NT; i += 256) atomicAdd(&hist[enc_t[i] >> 8], 1);
    __syncthreads();
    if (tid == 0) {
        int cum = 0, b = 255;
        for (; b >= 0; b--) { cum += hist[b]; if (cum >= KTOP) break; }
        sbsel = b; sabove = cum - hist[b];
    }
    __syncthreads();
    const int bsel = sbsel;
    hist[tid] = 0;
    __syncthreads();
    for (int i = tid; i < NT; i += 256) {
        int e = enc_t[i];
        if ((e >> 8) == bsel) atomicAdd(&hist[e & 0xFF], 1);
    }
    __syncthreads();
    if (tid == 0) {
        int cum = sabove, lb = 255;
        for (; lb >= 0; lb--) { cum += hist[lb]; if (cum >= KTOP) break; }
        st32e = (bsel << 8) | lb;
    }
    __syncthreads();
    const float thr = dec_enc(st32e) - TMARGIN;   // covers exact top-32 (margin >> 2*delta)

    // --- select tiles with max >= thr ---
    for (int i = tid; i < NT; i += 256) {
        if (dec_enc(enc_t[i]) >= thr) {          // NaN (phantom) compares false
            int p = atomicAdd(&ntiles, 1);
            if (p < TCAP) tiles[p] = i;
        }
    }
    __syncthreads();
    const int nt = ntiles < TCAP ? ntiles : TCAP;

    // --- scan selected tiles, collect candidates >= thr ---
    for (int idx = tid; idx < nt * BN; idx += 256) {
        int col = tiles[idx >> 7] * BN + (idx & 127);
        if (col < NKEYS) {
            float v = bf2f(scores[(size_t)n * NKEYS + col]);
            if (v >= thr) {
                int p = atomicAdd(&ncand, 1);
                if (p < CCAP) cand[p] = col;
            }
        }
    }
    __syncthreads();
    const int cnt = ncand < CCAP ? ncand : CCAP;

    // --- refine: exact dot(x_row, keys[cand]) with f64 accum, one wave/cand ---
    for (int ci = w; ci < cnt; ci += 4) {
        const f32x4* kv = reinterpret_cast<const f32x4*>(keys + (size_t)cand[ci] * DDIM) + lane * 4;
        const f32x4* qv = reinterpret_cast<const f32x4*>(qs) + lane * 4;
        double a = 0.0;
#pragma unroll
        for (int i = 0; i < 4; i++) {
            f32x4 q = qv[i], k = kv[i];
            a += (double)q.x * k.x + (double)q.y * k.y + (double)q.z * k.z + (double)q.w * k.w;
        }
#pragma unroll
        for (int sft = 32; sft >= 1; sft >>= 1) a += __shfl_xor(a, sft);
        if (lane == 0) rsc[ci] = a;
    }
    __syncthreads();

    // --- exact top-32 among candidates (wave 0, 4 slots covers CCAP=256) ---
    if (w == 0) {
        double v0[4]; int id0[4];
#pragma unroll
        for (int sft = 0; sft < 4; sft++) {
            int p = lane + sft * 64;
            if (p < cnt) { v0[sft] = rsc[p]; id0[sft] = p; } else { v0[sft] = -1e300; id0[sft] = -1; }
        }
        for (int k = 0; k < KTOP; k++) {
            double bv = v0[0]; int bi = id0[0];
#pragma unroll
            for (int sft = 1; sft < 4; sft++) if (v0[sft] > bv) { bv = v0[sft]; bi = id0[sft]; }
#pragma unroll
            for (int sft = 32; sft >= 1; sft >>= 1) {
                double ov = __shfl_xor(bv, sft);
                int    oi = __shfl_xor(bi, sft);
                if (ov > bv) { bv = ov; bi = oi; }
            }
            if (lane == 0) { topslot[k] = bi; topval[k] = (float)bv; }
#pragma unroll
            for (int sft = 0; sft < 4; sft++) if (bi >= 0 && id0[sft] == bi) v0[sft] = -1e300;
        }
    }
    __syncthreads();

    // --- softmax over the 32 exact scores ---
    if (tid == 0) {
        float mx = topval[0];
        float sum = 0.f;
        for (int k = 0; k < KTOP; k++) {
            float e = (topslot[k] >= 0) ? expf(topval[k] - mx) : 0.f;
            wgt[k] = e; sum += e;
        }
        float inv = 1.f / sum;
        for (int k = 0; k < KTOP; k++) wgt[k] *= inv;
    }
    __syncthreads();

    // --- output: weighted sum of selected vals rows ---
    f32x4 accv = (f32x4){0.f, 0.f, 0.f, 0.f};
    for (int k = 0; k < KTOP; k++) {
        int sl = topslot[k];
        if (sl >= 0) {
            float wk = wgt[k];
            f32x4 v = reinterpret_cast<const f32x4*>(vals + (size_t)cand[sl] * DDIM)[tid];
            accv.x += wk * v.x; accv.y += wk * v.y; accv.z += wk * v.z; accv.w += wk * v.w;
        }
    }
    reinterpret_cast<f32x4*>(out + (size_t)n * DDIM)[tid] = accv;
}

// ---------------------------------------------------------------- launch
extern "C" void kernel_launch(void* const* d_in, const int* in_sizes, int n_in,
                              void* d_out, int out_size, void* d_ws, size_t ws_size,
                              hipStream_t stream) {
    const float* x    = (const float*)d_in[0];
    const float* keys = (const float*)d_in[1];
    const float* vals = (const float*)d_in[2];
    float* out = (float*)d_out;

    char* ws = (char*)d_ws;
    unsigned short* scores  = (unsigned short*)ws;                         // 204,800,000 B
    unsigned short* xb      = (unsigned short*)(ws + 204800000);           //   1,048,576 B
    unsigned short* tilemax = (unsigned short*)(ws + 204800000 + 1048576); //   1,605,632 B

    cvt_x_kernel<<<512, 256, 0, stream>>>(x, xb);
    score_gemm<<<4 * NT, 256, 0, stream>>>(keys, xb, scores, tilemax);
    select_kernel<<<MROWS, 256, 0, stream>>>(x, keys, vals, scores, tilemax, out);
}